// Round 1
// baseline (947.123 us; speedup 1.0000x reference)
//
#include <hip/hip_runtime.h>

#define NHEADS 16
#define HDIM 2048
#define HN 128
#define SS 2048

typedef short short8 __attribute__((ext_vector_type(8)));
typedef __bf16 bf16x8 __attribute__((ext_vector_type(8)));
typedef float f32x4 __attribute__((ext_vector_type(4)));

__device__ __forceinline__ unsigned short f2bf(float f) {
  unsigned int u = __float_as_uint(f);
  u += 0x7FFFu + ((u >> 16) & 1u);
  return (unsigned short)(u >> 16);
}
__device__ __forceinline__ bf16x8 ld8(const void* p) {
  short8 s = *(const short8*)p;
  return __builtin_bit_cast(bf16x8, s);
}
__device__ __forceinline__ void gld_lds16(const void* g, void* l) {
  __builtin_amdgcn_global_load_lds(
      (const __attribute__((address_space(1))) unsigned int*)g,
      (__attribute__((address_space(3))) unsigned int*)l, 16, 0, 0);
}

// ---------------- cast fp32 -> bf16 (vectorized) ----------------
__global__ __launch_bounds__(256) void cast_bf16_kernel(
    const float* __restrict__ in, unsigned short* __restrict__ out, int n4) {
  int i = blockIdx.x * 256 + threadIdx.x;
  if (i >= n4) return;
  float4 v = ((const float4*)in)[i];
  ushort4 o;
  o.x = f2bf(v.x); o.y = f2bf(v.y); o.z = f2bf(v.z); o.w = f2bf(v.w);
  ((ushort4*)out)[i] = o;
}

// ---------------- transpose + cast: in[R][C] fp32 -> out[C][R] bf16 ----------------
__global__ __launch_bounds__(256) void transpose_cast_kernel(
    const float* __restrict__ in, unsigned short* __restrict__ out, int R, int C) {
  __shared__ float tile[64][65];
  int tx = threadIdx.x & 63, ty = threadIdx.x >> 6;
  int c0 = blockIdx.x * 64, r0 = blockIdx.y * 64;
#pragma unroll
  for (int i = 0; i < 16; ++i) {
    int r = ty + i * 4;
    tile[r][tx] = in[(size_t)(r0 + r) * C + (c0 + tx)];
  }
  __syncthreads();
#pragma unroll
  for (int i = 0; i < 16; ++i) {
    int r = ty + i * 4;
    out[(size_t)(c0 + r) * R + (r0 + tx)] = f2bf(tile[tx][r]);
  }
}

// ---------------- bf16 GEMM, A[M][K] x Bt[N][K] (m97 structure) ----------------
// EPI=0: scatter to Q/K/V [B,NH,S,HN] bf16 with bias.  EPI=1: fp32 out + bias.
template <int EPI>
__global__ __launch_bounds__(256) void gemm_bt_kernel(
    const unsigned short* __restrict__ A, const unsigned short* __restrict__ Bt,
    const float* __restrict__ bias, float* __restrict__ Of,
    unsigned short* __restrict__ Oq, unsigned short* __restrict__ Ok,
    unsigned short* __restrict__ Ov, int M, int N, int K) {
  __shared__ __align__(16) unsigned short At[128 * 32];
  __shared__ __align__(16) unsigned short Bs[128 * 32];
  int t = threadIdx.x;
  int lane = t & 63, wid = t >> 6;
  int wr = wid >> 1, wc = wid & 1;
  int brow = blockIdx.y * 128;
  int bcol = blockIdx.x * 128;
  const unsigned short* Ab = A + (size_t)brow * K;
  const unsigned short* Bb = Bt + (size_t)bcol * K;
  f32x4 acc[4][4];
#pragma unroll
  for (int m = 0; m < 4; ++m)
#pragma unroll
    for (int n = 0; n < 4; ++n) acc[m][n] = (f32x4){0.f, 0.f, 0.f, 0.f};
  int c0 = t, c1 = t + 256;
  int r0c = c0 >> 2, s0c = (c0 & 3) * 8;
  int r1c = c1 >> 2, s1c = (c1 & 3) * 8;
  for (int kt = 0; kt < K; kt += 32) {
    gld_lds16(Ab + (size_t)r0c * K + kt + s0c, At + c0 * 8);
    gld_lds16(Ab + (size_t)r1c * K + kt + s1c, At + c1 * 8);
    gld_lds16(Bb + (size_t)r0c * K + kt + s0c, Bs + c0 * 8);
    gld_lds16(Bb + (size_t)r1c * K + kt + s1c, Bs + c1 * 8);
    __syncthreads();
    bf16x8 af[4], bfr[4];
    int koff = (lane >> 4) * 8;
    int ar = wr * 64 + (lane & 15);
    int br = wc * 64 + (lane & 15);
#pragma unroll
    for (int m = 0; m < 4; ++m) af[m] = ld8(At + (ar + m * 16) * 32 + koff);
#pragma unroll
    for (int n = 0; n < 4; ++n) bfr[n] = ld8(Bs + (br + n * 16) * 32 + koff);
#pragma unroll
    for (int m = 0; m < 4; ++m)
#pragma unroll
      for (int n = 0; n < 4; ++n)
        acc[m][n] = __builtin_amdgcn_mfma_f32_16x16x32_bf16(af[m], bfr[n], acc[m][n], 0, 0, 0);
    __syncthreads();
  }
  if (EPI == 0) {
    int which = bcol >> 11;
    int headb = (bcol & 2047) >> 7;
    unsigned short* dst = which == 0 ? Oq : (which == 1 ? Ok : Ov);
#pragma unroll
    for (int m = 0; m < 4; ++m) {
      int rbase = brow + wr * 64 + m * 16 + ((lane >> 4) * 4);
#pragma unroll
      for (int n = 0; n < 4; ++n) {
        int d = wc * 64 + n * 16 + (lane & 15);
        float bv = bias[bcol + d];
#pragma unroll
        for (int j = 0; j < 4; ++j) {
          int rr = rbase + j;
          int b = rr >> 11, s = rr & 2047;
          dst[((size_t)(b * NHEADS + headb) * SS + s) * HN + d] = f2bf(acc[m][n][j] + bv);
        }
      }
    }
  } else {
#pragma unroll
    for (int m = 0; m < 4; ++m) {
      int rbase = brow + wr * 64 + m * 16 + ((lane >> 4) * 4);
#pragma unroll
      for (int n = 0; n < 4; ++n) {
        int cc = bcol + wc * 64 + n * 16 + (lane & 15);
        float bv = bias[cc];
#pragma unroll
        for (int j = 0; j < 4; ++j)
          Of[(size_t)(rbase + j) * N + cc] = acc[m][n][j] + bv;
      }
    }
  }
}

// ---------------- causal flash attention ----------------
// Q/K/V: [B*NH][S][HN] bf16. ctx out: [B*S][H] bf16.
__global__ __launch_bounds__(256) void attn_kernel(
    const unsigned short* __restrict__ Q, const unsigned short* __restrict__ Kb,
    const unsigned short* __restrict__ Vb, unsigned short* __restrict__ ctx) {
  __shared__ __align__(16) unsigned short Klds[64 * 128];   // swizzled
  __shared__ __align__(16) unsigned short Vt[128 * 72];     // transposed, pad 72
  __shared__ __align__(16) unsigned short Plds[4][16 * 72];
  int t = threadIdx.x, lane = t & 63, wid = t >> 6;
  int qi = blockIdx.x, bh = blockIdx.y;
  int q0 = qi * 64;
  const unsigned short* Qb = Q + (size_t)bh * SS * HN;
  const unsigned short* Kbh = Kb + (size_t)bh * SS * HN;
  const unsigned short* Vbh = Vb + (size_t)bh * SS * HN;
  bf16x8 qf[4];
  int qrow = q0 + wid * 16 + (lane & 15);
#pragma unroll
  for (int dsi = 0; dsi < 4; ++dsi)
    qf[dsi] = ld8(Qb + (size_t)qrow * HN + dsi * 32 + (lane >> 4) * 8);
  f32x4 o[8];
#pragma unroll
  for (int n = 0; n < 8; ++n) o[n] = (f32x4){0.f, 0.f, 0.f, 0.f};
  float m_run[4], l_run[4];
#pragma unroll
  for (int j = 0; j < 4; ++j) { m_run[j] = -1e30f; l_run[j] = 0.f; }
  const float scale = 0.08838834764831845f;

  for (int kt = 0; kt <= qi; ++kt) {
    int k0 = kt * 64;
    __syncthreads();  // previous tile fully consumed
    {  // stage K with both-sides XOR swizzle (pre-swizzled source, linear LDS dest)
      const char* Ks = (const char*)(Kbh + (size_t)k0 * HN);
#pragma unroll
      for (int i = 0; i < 4; ++i) {
        int c = t + i * 256;
        int sb = (c * 16) ^ (((c >> 4) & 7) << 4);
        gld_lds16(Ks + sb, (char*)Klds + c * 16);
      }
    }
    {  // stage V transposed: Vt[d][key]
      int key = t & 63, dblk = t >> 6;
      const unsigned short* Vr = Vbh + (size_t)(k0 + key) * HN + dblk * 32;
#pragma unroll
      for (int i = 0; i < 4; ++i) {
        short8 v = *(const short8*)(Vr + i * 8);
#pragma unroll
        for (int e = 0; e < 8; ++e)
          Vt[(dblk * 32 + i * 8 + e) * 72 + key] = (unsigned short)v[e];
      }
    }
    __syncthreads();
    // QK^T: A=Q[16q x 32d], B=K^T[32d x 16k]
    f32x4 sacc[4];
#pragma unroll
    for (int f = 0; f < 4; ++f) sacc[f] = (f32x4){0.f, 0.f, 0.f, 0.f};
#pragma unroll
    for (int f = 0; f < 4; ++f) {
      int keyl = f * 16 + (lane & 15);
      int swz = (keyl & 7) << 4;
#pragma unroll
      for (int dsi = 0; dsi < 4; ++dsi) {
        int off = (keyl * 256 + (dsi * 32 + (lane >> 4) * 8) * 2) ^ swz;
        bf16x8 kf = ld8((const char*)Klds + off);
        sacc[f] = __builtin_amdgcn_mfma_f32_16x16x32_bf16(qf[dsi], kf, sacc[f], 0, 0, 0);
      }
    }
    // online softmax (rows = (lane>>4)*4+j, keys across lane&15 and f)
    bool diag = (kt == qi);
    float pm[4], sv[4][4];
#pragma unroll
    for (int j = 0; j < 4; ++j) pm[j] = -1e30f;
#pragma unroll
    for (int f = 0; f < 4; ++f) {
      int key_g = k0 + f * 16 + (lane & 15);
#pragma unroll
      for (int j = 0; j < 4; ++j) {
        int q_g = q0 + wid * 16 + (lane >> 4) * 4 + j;
        float s = sacc[f][j] * scale;
        if (diag && key_g > q_g) s = -1e30f;
        sv[f][j] = s;
        pm[j] = fmaxf(pm[j], s);
      }
    }
#pragma unroll
    for (int j = 0; j < 4; ++j) {
#pragma unroll
      for (int off = 1; off < 16; off <<= 1)
        pm[j] = fmaxf(pm[j], __shfl_xor(pm[j], off, 16));
    }
    float resc[4], rs[4];
#pragma unroll
    for (int j = 0; j < 4; ++j) {
      float mn = fmaxf(m_run[j], pm[j]);
      resc[j] = __expf(m_run[j] - mn);
      m_run[j] = mn;
      rs[j] = 0.f;
    }
#pragma unroll
    for (int f = 0; f < 4; ++f) {
#pragma unroll
      for (int j = 0; j < 4; ++j) {
        float p = __expf(sv[f][j] - m_run[j]);
        rs[j] += p;
        Plds[wid][((lane >> 4) * 4 + j) * 72 + f * 16 + (lane & 15)] = f2bf(p);
      }
    }
#pragma unroll
    for (int j = 0; j < 4; ++j) {
#pragma unroll
      for (int off = 1; off < 16; off <<= 1) rs[j] += __shfl_xor(rs[j], off, 16);
      l_run[j] = l_run[j] * resc[j] + rs[j];
    }
#pragma unroll
    for (int n = 0; n < 8; ++n)
#pragma unroll
      for (int j = 0; j < 4; ++j) o[n][j] *= resc[j];
    // PV: A=P[16q x 32k], B=V[32k x 16d] from Vt
#pragma unroll
    for (int ks = 0; ks < 2; ++ks) {
      bf16x8 pa = ld8(&Plds[wid][(lane & 15) * 72 + ks * 32 + (lane >> 4) * 8]);
#pragma unroll
      for (int n = 0; n < 8; ++n) {
        bf16x8 vf = ld8(&Vt[(n * 16 + (lane & 15)) * 72 + ks * 32 + (lane >> 4) * 8]);
        o[n] = __builtin_amdgcn_mfma_f32_16x16x32_bf16(pa, vf, o[n], 0, 0, 0);
      }
    }
  }
  int b = bh >> 4, head = bh & 15;
#pragma unroll
  for (int n = 0; n < 8; ++n) {
#pragma unroll
    for (int j = 0; j < 4; ++j) {
      int qg = q0 + wid * 16 + (lane >> 4) * 4 + j;
      float val = o[n][j] / l_run[j];
      ctx[(size_t)(b * SS + qg) * HDIM + head * HN + n * 16 + (lane & 15)] = f2bf(val);
    }
  }
}

extern "C" void kernel_launch(void* const* d_in, const int* in_sizes, int n_in,
                              void* d_out, int out_size, void* d_ws, size_t ws_size,
                              hipStream_t stream) {
  const float* hs = (const float*)d_in[0];
  // d_in[1] = ltor_mask: causal, handled analytically
  const float* w_qkv = (const float*)d_in[2];
  const float* b_qkv = (const float*)d_in[3];
  const float* w_dense = (const float*)d_in[4];
  const float* b_dense = (const float*)d_in[5];
  float* out = (float*)d_out;

  char* ws = (char*)d_ws;
  unsigned short* hsb   = (unsigned short*)(ws);              // 33.5 MB (reused as ctx)
  unsigned short* wqkvT = (unsigned short*)(ws + 33554432);   // 25.2 MB (reused as wdT)
  unsigned short* qb    = (unsigned short*)(ws + 58720256);   // 33.5 MB
  unsigned short* kb    = (unsigned short*)(ws + 92274688);   // 33.5 MB
  unsigned short* vb    = (unsigned short*)(ws + 125829120);  // 33.5 MB -> 152 MB total
  unsigned short* ctxb  = hsb;    // hs consumed by qkv GEMM before attention writes ctx
  unsigned short* wdT   = wqkvT;  // wqkvT consumed by qkv GEMM before dense transpose

  cast_bf16_kernel<<<16384, 256, 0, stream>>>(hs, hsb, 4194304);
  transpose_cast_kernel<<<dim3(96, 32), 256, 0, stream>>>(w_qkv, wqkvT, 2048, 6144);
  gemm_bt_kernel<0><<<dim3(48, 64), 256, 0, stream>>>(
      hsb, wqkvT, b_qkv, nullptr, qb, kb, vb, 8192, 6144, 2048);
  transpose_cast_kernel<<<dim3(32, 32), 256, 0, stream>>>(w_dense, wdT, 2048, 2048);
  attn_kernel<<<dim3(32, 64), 256, 0, stream>>>(qb, kb, vb, ctxb);
  gemm_bt_kernel<1><<<dim3(16, 64), 256, 0, stream>>>(
      ctxb, wdT, b_dense, out, nullptr, nullptr, nullptr, 8192, 2048, 2048);
}

// Round 3
// 852.968 us; speedup vs baseline: 1.1104x; 1.1104x over previous
//
#include <hip/hip_runtime.h>

#define NHEADS 16
#define HDIM 2048
#define HN 128
#define SS 2048

typedef short short8 __attribute__((ext_vector_type(8)));
typedef __bf16 bf16x8 __attribute__((ext_vector_type(8)));
typedef float f32x4 __attribute__((ext_vector_type(4)));

__device__ __forceinline__ unsigned short f2bf(float f) {
  unsigned int u = __float_as_uint(f);
  u += 0x7FFFu + ((u >> 16) & 1u);
  return (unsigned short)(u >> 16);
}
__device__ __forceinline__ bf16x8 ld8(const void* p) {
  short8 s = *(const short8*)p;
  return __builtin_bit_cast(bf16x8, s);
}
__device__ __forceinline__ void gld_lds16(const void* g, void* l) {
  __builtin_amdgcn_global_load_lds(
      (const __attribute__((address_space(1))) unsigned int*)g,
      (__attribute__((address_space(3))) unsigned int*)l, 16, 0, 0);
}

// ---------------- cast fp32 -> bf16 (vectorized) ----------------
__global__ __launch_bounds__(256) void cast_bf16_kernel(
    const float* __restrict__ in, unsigned short* __restrict__ out, int n4) {
  int i = blockIdx.x * 256 + threadIdx.x;
  if (i >= n4) return;
  float4 v = ((const float4*)in)[i];
  ushort4 o;
  o.x = f2bf(v.x); o.y = f2bf(v.y); o.z = f2bf(v.z); o.w = f2bf(v.w);
  ((ushort4*)out)[i] = o;
}

// ---------------- transpose + cast: in[R][C] fp32 -> out[C][R] bf16 ----------------
__global__ __launch_bounds__(256) void transpose_cast_kernel(
    const float* __restrict__ in, unsigned short* __restrict__ out, int R, int C) {
  __shared__ float tile[64][65];
  int tx = threadIdx.x & 63, ty = threadIdx.x >> 6;
  int c0 = blockIdx.x * 64, r0 = blockIdx.y * 64;
#pragma unroll
  for (int i = 0; i < 16; ++i) {
    int r = ty + i * 4;
    tile[r][tx] = in[(size_t)(r0 + r) * C + (c0 + tx)];
  }
  __syncthreads();
#pragma unroll
  for (int i = 0; i < 16; ++i) {
    int r = ty + i * 4;
    out[(size_t)(c0 + r) * R + (r0 + tx)] = f2bf(tile[tx][r]);
  }
}

// ---------------- bf16 GEMM, A[M][K] x Bt[N][K] (m97 structure) ----------------
// EPI=0: Q/K scattered to [B,NH,S,HN] bf16; V written TRANSPOSED to [B,NH,HN,S].
// EPI=1: fp32 out + bias.
template <int EPI>
__global__ __launch_bounds__(256) void gemm_bt_kernel(
    const unsigned short* __restrict__ A, const unsigned short* __restrict__ Bt,
    const float* __restrict__ bias, float* __restrict__ Of,
    unsigned short* __restrict__ Oq, unsigned short* __restrict__ Ok,
    unsigned short* __restrict__ Ovt, int M, int N, int K) {
  __shared__ __align__(16) unsigned short At[128 * 32];
  __shared__ __align__(16) unsigned short Bs[128 * 32];
  int t = threadIdx.x;
  int lane = t & 63, wid = t >> 6;
  int wr = wid >> 1, wc = wid & 1;
  int brow = blockIdx.y * 128;
  int bcol = blockIdx.x * 128;
  const unsigned short* Ab = A + (size_t)brow * K;
  const unsigned short* Bb = Bt + (size_t)bcol * K;
  f32x4 acc[4][4];
#pragma unroll
  for (int m = 0; m < 4; ++m)
#pragma unroll
    for (int n = 0; n < 4; ++n) acc[m][n] = (f32x4){0.f, 0.f, 0.f, 0.f};
  int c0 = t, c1 = t + 256;
  int r0c = c0 >> 2, s0c = (c0 & 3) * 8;
  int r1c = c1 >> 2, s1c = (c1 & 3) * 8;
  for (int kt = 0; kt < K; kt += 32) {
    gld_lds16(Ab + (size_t)r0c * K + kt + s0c, At + c0 * 8);
    gld_lds16(Ab + (size_t)r1c * K + kt + s1c, At + c1 * 8);
    gld_lds16(Bb + (size_t)r0c * K + kt + s0c, Bs + c0 * 8);
    gld_lds16(Bb + (size_t)r1c * K + kt + s1c, Bs + c1 * 8);
    __syncthreads();
    bf16x8 af[4], bfr[4];
    int koff = (lane >> 4) * 8;
    int ar = wr * 64 + (lane & 15);
    int br = wc * 64 + (lane & 15);
#pragma unroll
    for (int m = 0; m < 4; ++m) af[m] = ld8(At + (ar + m * 16) * 32 + koff);
#pragma unroll
    for (int n = 0; n < 4; ++n) bfr[n] = ld8(Bs + (br + n * 16) * 32 + koff);
#pragma unroll
    for (int m = 0; m < 4; ++m)
#pragma unroll
      for (int n = 0; n < 4; ++n)
        acc[m][n] = __builtin_amdgcn_mfma_f32_16x16x32_bf16(af[m], bfr[n], acc[m][n], 0, 0, 0);
    __syncthreads();
  }
  if (EPI == 0) {
    int which = bcol >> 11;
    int headb = (bcol & 2047) >> 7;
    if (which == 2) {
      // V third: write transposed [b,h][d][s], 8-B vector stores (4 consecutive s)
#pragma unroll
      for (int m = 0; m < 4; ++m) {
        int rbase = brow + wr * 64 + m * 16 + ((lane >> 4) * 4);
        int b = rbase >> 11, s = rbase & 2047;  // rbase..rbase+3 same b (mult of 4)
#pragma unroll
        for (int n = 0; n < 4; ++n) {
          int d = wc * 64 + n * 16 + (lane & 15);
          float bv = bias[bcol + d];
          ushort4 pk;
          pk.x = f2bf(acc[m][n][0] + bv);
          pk.y = f2bf(acc[m][n][1] + bv);
          pk.z = f2bf(acc[m][n][2] + bv);
          pk.w = f2bf(acc[m][n][3] + bv);
          *(ushort4*)&Ovt[((size_t)(b * NHEADS + headb) * HN + d) * SS + s] = pk;
        }
      }
    } else {
      unsigned short* dst = which == 0 ? Oq : Ok;
#pragma unroll
      for (int m = 0; m < 4; ++m) {
        int rbase = brow + wr * 64 + m * 16 + ((lane >> 4) * 4);
#pragma unroll
        for (int n = 0; n < 4; ++n) {
          int d = wc * 64 + n * 16 + (lane & 15);
          float bv = bias[bcol + d];
#pragma unroll
          for (int j = 0; j < 4; ++j) {
            int rr = rbase + j;
            int b = rr >> 11, s = rr & 2047;
            dst[((size_t)(b * NHEADS + headb) * SS + s) * HN + d] = f2bf(acc[m][n][j] + bv);
          }
        }
      }
    }
  } else {
#pragma unroll
    for (int m = 0; m < 4; ++m) {
      int rbase = brow + wr * 64 + m * 16 + ((lane >> 4) * 4);
#pragma unroll
      for (int n = 0; n < 4; ++n) {
        int cc = bcol + wc * 64 + n * 16 + (lane & 15);
        float bv = bias[cc];
#pragma unroll
        for (int j = 0; j < 4; ++j)
          Of[(size_t)(rbase + j) * N + cc] = acc[m][n][j] + bv;
      }
    }
  }
}

// ---------------- causal flash attention v3 ----------------
// 4 waves x 32 q-rows = 128 q-rows/block. KVBLK=64.
// K [key][d] and Vt [d][key] staged via global_load_lds with both-sides XOR
// swizzle (proven v1 pattern). P row-major [q][key] per-wave, scalar writes +
// ld8 reads (proven v1 pattern). No tr_read.
__global__ __launch_bounds__(256, 2) void attn_kernel(
    const unsigned short* __restrict__ Q, const unsigned short* __restrict__ Kb,
    const unsigned short* __restrict__ Vt, unsigned short* __restrict__ ctx) {
  __shared__ __align__(16) unsigned short Klds[64 * 128];    // 16 KB, [key][d] swz
  __shared__ __align__(16) unsigned short Vlds[128 * 64];    // 16 KB, [d][key] swz
  __shared__ __align__(16) unsigned short Plds[4][32 * 72];  // 18 KB, [wave][q][key]
  int t = threadIdx.x, lane = t & 63, wid = t >> 6;
  int g = lane >> 4, ln15 = lane & 15;
  int qi = (int)(gridDim.x - 1) - (int)blockIdx.x;  // long blocks first
  int bh = blockIdx.y;
  int q0 = qi * 128;
  int qbase = q0 + wid * 32;
  const unsigned short* Qb = Q + (size_t)bh * SS * HN;
  const unsigned short* Kbh = Kb + (size_t)bh * SS * HN;
  const unsigned short* Vtb = Vt + (size_t)bh * HN * SS;  // [d][s]

  bf16x8 qf[2][4];
#pragma unroll
  for (int mr = 0; mr < 2; ++mr) {
    int qrow = qbase + mr * 16 + ln15;
#pragma unroll
    for (int dsi = 0; dsi < 4; ++dsi)
      qf[mr][dsi] = ld8(Qb + (size_t)qrow * HN + dsi * 32 + g * 8);
  }
  f32x4 o[2][8];
#pragma unroll
  for (int mr = 0; mr < 2; ++mr)
#pragma unroll
    for (int n = 0; n < 8; ++n) o[mr][n] = (f32x4){0.f, 0.f, 0.f, 0.f};
  float m_run[2][4], l_run[2][4];
#pragma unroll
  for (int mr = 0; mr < 2; ++mr)
#pragma unroll
    for (int j = 0; j < 4; ++j) { m_run[mr][j] = -1e30f; l_run[mr][j] = 0.f; }
  const float scale = 0.08838834764831845f;
  unsigned short* Pw = Plds[wid];

  int nkt = 2 * qi + 2;
  for (int kt = 0; kt < nkt; ++kt) {
    int k0 = kt * 64;
    __syncthreads();  // previous tile fully consumed
    {  // stage K: 64 rows x 256 B, both-sides XOR swizzle
      const char* Ks = (const char*)(Kbh + (size_t)k0 * HN);
#pragma unroll
      for (int i = 0; i < 4; ++i) {
        int c = t + i * 256;
        int sb = (c * 16) ^ (((c >> 4) & 7) << 4);
        gld_lds16(Ks + sb, (char*)Klds + c * 16);
      }
    }
    {  // stage Vt tile: 128 rows x 128 B (row stride SS in global), swizzled
#pragma unroll
      for (int i = 0; i < 4; ++i) {
        int c = t + i * 256;
        int row = c >> 3;
        int colsw = ((c & 7) * 16) ^ ((row & 7) << 4);
        gld_lds16((const char*)(Vtb + (size_t)row * SS + k0) + colsw,
                  (char*)Vlds + c * 16);
      }
    }
    __syncthreads();
    bool active = (k0 <= qbase + 31);  // wave-uniform; barriers stay uniform
    if (active) {
      // ---- QK^T ----
      f32x4 sacc[2][4];
#pragma unroll
      for (int mr = 0; mr < 2; ++mr)
#pragma unroll
        for (int f = 0; f < 4; ++f) sacc[mr][f] = (f32x4){0.f, 0.f, 0.f, 0.f};
      __builtin_amdgcn_s_setprio(1);
#pragma unroll
      for (int f = 0; f < 4; ++f) {
        int keyl = f * 16 + ln15;
        int swzk = (keyl & 7) << 4;
#pragma unroll
        for (int dsi = 0; dsi < 4; ++dsi) {
          int off = (keyl * 256 + (dsi * 32 + g * 8) * 2) ^ swzk;
          bf16x8 kf = ld8((const char*)Klds + off);
          sacc[0][f] = __builtin_amdgcn_mfma_f32_16x16x32_bf16(qf[0][dsi], kf, sacc[0][f], 0, 0, 0);
          sacc[1][f] = __builtin_amdgcn_mfma_f32_16x16x32_bf16(qf[1][dsi], kf, sacc[1][f], 0, 0, 0);
        }
      }
      __builtin_amdgcn_s_setprio(0);
      // ---- online softmax ----
      float resc[2][4], rs[2][4];
#pragma unroll
      for (int mr = 0; mr < 2; ++mr) {
        bool needmask = (k0 + 63) > (qbase + mr * 16);
        float pm[4];
#pragma unroll
        for (int j = 0; j < 4; ++j) pm[j] = -1e30f;
#pragma unroll
        for (int f = 0; f < 4; ++f) {
          int key_g = k0 + f * 16 + ln15;
#pragma unroll
          for (int j = 0; j < 4; ++j) {
            float s = sacc[mr][f][j] * scale;
            if (needmask) {
              int q_g = qbase + mr * 16 + g * 4 + j;
              if (key_g > q_g) s = -1e30f;
            }
            sacc[mr][f][j] = s;
            pm[j] = fmaxf(pm[j], s);
          }
        }
#pragma unroll
        for (int j = 0; j < 4; ++j) {
          float v = pm[j];
          v = fmaxf(v, __shfl_xor(v, 1, 16));
          v = fmaxf(v, __shfl_xor(v, 2, 16));
          v = fmaxf(v, __shfl_xor(v, 4, 16));
          v = fmaxf(v, __shfl_xor(v, 8, 16));
          float mn = fmaxf(m_run[mr][j], v);
          resc[mr][j] = __expf(m_run[mr][j] - mn);
          m_run[mr][j] = mn;
          rs[mr][j] = 0.f;
        }
#pragma unroll
        for (int f = 0; f < 4; ++f) {
#pragma unroll
          for (int j = 0; j < 4; ++j) {
            float p = __expf(sacc[mr][f][j] - m_run[mr][j]);
            rs[mr][j] += p;
            Pw[(mr * 16 + g * 4 + j) * 72 + f * 16 + ln15] = f2bf(p);
          }
        }
#pragma unroll
        for (int j = 0; j < 4; ++j) {
          float v = rs[mr][j];
          v += __shfl_xor(v, 1, 16);
          v += __shfl_xor(v, 2, 16);
          v += __shfl_xor(v, 4, 16);
          v += __shfl_xor(v, 8, 16);
          l_run[mr][j] = l_run[mr][j] * resc[mr][j] + v;
        }
#pragma unroll
        for (int n = 0; n < 8; ++n)
#pragma unroll
          for (int j = 0; j < 4; ++j) o[mr][n][j] *= resc[mr][j];
      }
      // ---- PV ----
#pragma unroll
      for (int ks = 0; ks < 2; ++ks) {
        bf16x8 pa0 = ld8(&Pw[(size_t)(ln15)*72 + ks * 32 + g * 8]);
        bf16x8 pa1 = ld8(&Pw[(size_t)(16 + ln15) * 72 + ks * 32 + g * 8]);
        __builtin_amdgcn_s_setprio(1);
#pragma unroll
        for (int n = 0; n < 8; ++n) {
          int d = n * 16 + ln15;
          int off = (d * 128 + ks * 64 + g * 16) ^ ((d & 7) << 4);
          bf16x8 vf = ld8((const char*)Vlds + off);
          o[0][n] = __builtin_amdgcn_mfma_f32_16x16x32_bf16(pa0, vf, o[0][n], 0, 0, 0);
          o[1][n] = __builtin_amdgcn_mfma_f32_16x16x32_bf16(pa1, vf, o[1][n], 0, 0, 0);
        }
        __builtin_amdgcn_s_setprio(0);
      }
    }
  }
  // ---- epilogue ----
  int b = bh >> 4, head = bh & 15;
#pragma unroll
  for (int mr = 0; mr < 2; ++mr)
#pragma unroll
    for (int j = 0; j < 4; ++j) {
      int qg = qbase + mr * 16 + g * 4 + j;
      float inv = 1.0f / l_run[mr][j];
      size_t base = ((size_t)(b * SS + qg)) * HDIM + head * HN + ln15;
#pragma unroll
      for (int n = 0; n < 8; ++n)
        ctx[base + n * 16] = f2bf(o[mr][n][j] * inv);
    }
}

extern "C" void kernel_launch(void* const* d_in, const int* in_sizes, int n_in,
                              void* d_out, int out_size, void* d_ws, size_t ws_size,
                              hipStream_t stream) {
  const float* hs = (const float*)d_in[0];
  // d_in[1] = ltor_mask: causal, handled analytically
  const float* w_qkv = (const float*)d_in[2];
  const float* b_qkv = (const float*)d_in[3];
  const float* w_dense = (const float*)d_in[4];
  const float* b_dense = (const float*)d_in[5];
  float* out = (float*)d_out;

  char* ws = (char*)d_ws;
  unsigned short* hsb   = (unsigned short*)(ws);              // 33.5 MB (reused as ctx)
  unsigned short* wqkvT = (unsigned short*)(ws + 33554432);   // 25.2 MB (reused as wdT)
  unsigned short* qb    = (unsigned short*)(ws + 58720256);   // 33.5 MB
  unsigned short* kb    = (unsigned short*)(ws + 92274688);   // 33.5 MB
  unsigned short* vtb   = (unsigned short*)(ws + 125829120);  // 33.5 MB (V transposed)
  unsigned short* ctxb  = hsb;
  unsigned short* wdT   = wqkvT;

  cast_bf16_kernel<<<16384, 256, 0, stream>>>(hs, hsb, 4194304);
  transpose_cast_kernel<<<dim3(96, 32), 256, 0, stream>>>(w_qkv, wqkvT, 2048, 6144);
  gemm_bt_kernel<0><<<dim3(48, 64), 256, 0, stream>>>(
      hsb, wqkvT, b_qkv, nullptr, qb, kb, vtb, 8192, 6144, 2048);
  transpose_cast_kernel<<<dim3(32, 32), 256, 0, stream>>>(w_dense, wdT, 2048, 2048);
  attn_kernel<<<dim3(16, 64), 256, 0, stream>>>(qb, kb, vtb, ctxb);
  gemm_bt_kernel<1><<<dim3(16, 64), 256, 0, stream>>>(
      ctxb, wdT, b_dense, out, nullptr, nullptr, nullptr, 8192, 2048, 2048);
}

// Round 4
// 679.298 us; speedup vs baseline: 1.3943x; 1.2557x over previous
//
#include <hip/hip_runtime.h>

#define NHEADS 16
#define HDIM 2048
#define HN 128
#define SS 2048

typedef short short8 __attribute__((ext_vector_type(8)));
typedef __bf16 bf16x8 __attribute__((ext_vector_type(8)));
typedef float f32x4 __attribute__((ext_vector_type(4)));

__device__ __forceinline__ unsigned short f2bf(float f) {
  unsigned int u = __float_as_uint(f);
  u += 0x7FFFu + ((u >> 16) & 1u);
  return (unsigned short)(u >> 16);
}
__device__ __forceinline__ bf16x8 ld8(const void* p) {
  short8 s = *(const short8*)p;
  return __builtin_bit_cast(bf16x8, s);
}
__device__ __forceinline__ void gld_lds16(const void* g, void* l) {
  __builtin_amdgcn_global_load_lds(
      (const __attribute__((address_space(1))) unsigned int*)g,
      (__attribute__((address_space(3))) unsigned int*)l, 16, 0, 0);
}

// ---------------- cast fp32 -> bf16 (vectorized) ----------------
__global__ __launch_bounds__(256) void cast_bf16_kernel(
    const float* __restrict__ in, unsigned short* __restrict__ out, int n4) {
  int i = blockIdx.x * 256 + threadIdx.x;
  if (i >= n4) return;
  float4 v = ((const float4*)in)[i];
  ushort4 o;
  o.x = f2bf(v.x); o.y = f2bf(v.y); o.z = f2bf(v.z); o.w = f2bf(v.w);
  ((ushort4*)out)[i] = o;
}

// ---------------- transpose + cast: in[R][C] fp32 -> out[C][R] bf16 ----------------
__global__ __launch_bounds__(256) void transpose_cast_kernel(
    const float* __restrict__ in, unsigned short* __restrict__ out, int R, int C) {
  __shared__ float tile[64][65];
  int tx = threadIdx.x & 63, ty = threadIdx.x >> 6;
  int c0 = blockIdx.x * 64, r0 = blockIdx.y * 64;
#pragma unroll
  for (int i = 0; i < 16; ++i) {
    int r = ty + i * 4;
    tile[r][tx] = in[(size_t)(r0 + r) * C + (c0 + tx)];
  }
  __syncthreads();
#pragma unroll
  for (int i = 0; i < 16; ++i) {
    int r = ty + i * 4;
    out[(size_t)(c0 + r) * R + (r0 + tx)] = f2bf(tile[tx][r]);
  }
}

// ================= 256x256 8-phase bf16 GEMM (T2+T3+T4+T5) =================
// A[M][K] x Bt[N][K]. 512 threads = 8 waves (2 m-waves x 4 n-waves).
// LDS: 2 buffers x (A 256x64 + B 256x64) bf16 = 128 KiB, row-XOR swizzled,
// staged via global_load_lds with pre-swizzled global source (rule #21).
// Rows permuted so each half-tile (128 LDS rows) is exactly one quadrant's need:
//   A lds row r -> m = (r&63) + ((r>>6)&1)*128 + ((r>>7)&1)*64
//   B lds row r -> n = (r&31) + ((r>>5)&3)*64  + ((r>>7)&1)*32
// K-tile t in buf[t&1]. Issue order per tile: A0,B0,B1,A1 (5-phase lead).
// vmcnt(6) at p0/p1/p3 ends (counted, never 0 in main loop); vmcnt(4) entering
// the last tile; peeled last tile drains 2->0.
// EPI=0: Q/K scatter to [B,NH,S,HN] bf16 + V transposed to [B,NH,HN,S].
// EPI=1: fp32 out + bias.

#define STAGE_A(bsel, h, kt)                                                      \
  do {                                                                            \
    gld_lds16((const char*)(Ab + (size_t)sa_m[h][0] * K + (size_t)(kt) * 64) +    \
                  scol0,                                                          \
              lds + (bsel) * 65536 + (h) * 16384 + t * 16);                       \
    gld_lds16((const char*)(Ab + (size_t)sa_m[h][1] * K + (size_t)(kt) * 64) +    \
                  scol1,                                                          \
              lds + (bsel) * 65536 + (h) * 16384 + (t + 512) * 16);               \
  } while (0)

#define STAGE_B(bsel, h, kt)                                                      \
  do {                                                                            \
    gld_lds16((const char*)(Bb + (size_t)sb_n[h][0] * K + (size_t)(kt) * 64) +    \
                  scol0,                                                          \
              lds + (bsel) * 65536 + 32768 + (h) * 16384 + t * 16);               \
    gld_lds16((const char*)(Bb + (size_t)sb_n[h][1] * K + (size_t)(kt) * 64) +    \
                  scol1,                                                          \
              lds + (bsel) * 65536 + 32768 + (h) * 16384 + (t + 512) * 16);       \
  } while (0)

#define LDA(bsel, mh)                                                             \
  do {                                                                            \
    _Pragma("unroll") for (int mf = 0; mf < 4; ++mf) {                            \
      int row = mf * 16 + ln15 + wr * 64 + (mh) * 128;                            \
      int sw = (row & 7) << 4;                                                    \
      const char* base = lds + (bsel) * 65536 + row * 128;                        \
      a[mf][0] = ld8(base + ((g * 16) ^ sw));                                     \
      a[mf][1] = ld8(base + ((64 + g * 16) ^ sw));                                \
    }                                                                             \
  } while (0)

#define LDB(bsel, nh, breg)                                                       \
  do {                                                                            \
    _Pragma("unroll") for (int nf = 0; nf < 2; ++nf) {                            \
      int row = nf * 16 + ln15 + wc * 32 + (nh) * 128;                            \
      int sw = (row & 7) << 4;                                                    \
      const char* base = lds + (bsel) * 65536 + 32768 + row * 128;                \
      breg[nf][0] = ld8(base + ((g * 16) ^ sw));                                  \
      breg[nf][1] = ld8(base + ((64 + g * 16) ^ sw));                             \
    }                                                                             \
  } while (0)

#define QMFMA(mh, nh, breg)                                                       \
  do {                                                                            \
    __builtin_amdgcn_s_setprio(1);                                                \
    _Pragma("unroll") for (int mf = 0; mf < 4; ++mf)                              \
        _Pragma("unroll") for (int nf = 0; nf < 2; ++nf)                          \
            _Pragma("unroll") for (int ks = 0; ks < 2; ++ks)                      \
                acc[(mh) * 4 + mf][(nh) * 2 + nf] =                               \
        __builtin_amdgcn_mfma_f32_16x16x32_bf16(                                  \
            a[mf][ks], breg[nf][ks], acc[(mh) * 4 + mf][(nh) * 2 + nf], 0, 0, 0); \
    __builtin_amdgcn_s_setprio(0);                                                \
  } while (0)

#define BARRIER asm volatile("s_barrier" ::: "memory")
#define VMCNT(n) asm volatile("s_waitcnt vmcnt(" #n ")" ::: "memory")

template <int EPI>
__global__ __launch_bounds__(512, 2) void gemm256_kernel(
    const unsigned short* __restrict__ A, const unsigned short* __restrict__ Bt,
    const float* __restrict__ bias, float* __restrict__ Of,
    unsigned short* __restrict__ Oq, unsigned short* __restrict__ Ok,
    unsigned short* __restrict__ Ovt, int M, int N, int K) {
  __shared__ __align__(16) char lds[131072];
  const int t = threadIdx.x;
  const int lane = t & 63, wid = t >> 6;
  const int wr = wid >> 2, wc = wid & 3;
  const int g = lane >> 4, ln15 = lane & 15;
  const int brow = blockIdx.y * 256, bcol = blockIdx.x * 256;
  const unsigned short* Ab = A + (size_t)brow * K;
  const unsigned short* Bb = Bt + (size_t)bcol * K;

  // staging precompute (idx0 = t, idx1 = t+512 within each 128-row half-tile)
  int r0 = t >> 3, r1 = (t + 512) >> 3;  // row within half (0..127)
  const int scol0 = ((t & 7) * 16) ^ ((r0 & 7) << 4);
  const int scol1 = (((t + 512) & 7) * 16) ^ ((r1 & 7) << 4);
  int sa_m[2][2], sb_n[2][2];
#pragma unroll
  for (int h = 0; h < 2; ++h) {
    int ra = h * 128 + r0, rb = h * 128 + r1;
    sa_m[h][0] = (ra & 63) + ((ra >> 6) & 1) * 128 + ((ra >> 7) & 1) * 64;
    sa_m[h][1] = (rb & 63) + ((rb >> 6) & 1) * 128 + ((rb >> 7) & 1) * 64;
    sb_n[h][0] = (ra & 31) + ((ra >> 5) & 3) * 64 + ((ra >> 7) & 1) * 32;
    sb_n[h][1] = (rb & 31) + ((rb >> 5) & 3) * 64 + ((rb >> 7) & 1) * 32;
  }

  f32x4 acc[8][4];
#pragma unroll
  for (int m = 0; m < 8; ++m)
#pragma unroll
    for (int n = 0; n < 4; ++n) acc[m][n] = (f32x4){0.f, 0.f, 0.f, 0.f};
  bf16x8 a[4][2], b0[2][2], b1[2][2];

  const int nt = K >> 6;
  // ---- prologue: A0[0],B0[0],B1[0],A1[0],A0[1] then retire A0[0],B0[0] ----
  STAGE_A(0, 0, 0);
  STAGE_B(0, 0, 0);
  STAGE_B(0, 1, 0);
  STAGE_A(0, 1, 0);
  STAGE_A(1, 0, 1);
  VMCNT(6);
  BARRIER;

  for (int tk = 0; tk < nt - 1; ++tk) {
    const int bsel = tk & 1, bnext = bsel ^ 1;
    // ---- p0: quadrant (m0,n0) ----
    LDA(bsel, 0);
    LDB(bsel, 0, b0);
    STAGE_B(bnext, 0, tk + 1);
    BARRIER;
    QMFMA(0, 0, b0);
    VMCNT(6);
    BARRIER;
    // ---- p1: (m0,n1) ----
    LDB(bsel, 1, b1);
    STAGE_B(bnext, 1, tk + 1);
    BARRIER;
    QMFMA(0, 1, b1);
    VMCNT(6);
    BARRIER;
    // ---- p2: (m1,n0) ----
    LDA(bsel, 1);
    STAGE_A(bnext, 1, tk + 1);
    BARRIER;
    QMFMA(1, 0, b0);
    BARRIER;
    // ---- p3: (m1,n1) ----
    if (tk + 2 < nt) STAGE_A(bsel, 0, tk + 2);
    BARRIER;
    QMFMA(1, 1, b1);
    if (tk < nt - 2) { VMCNT(6); } else { VMCNT(4); }
    BARRIER;
  }
  {  // ---- peeled last tile ----
    const int bsel = (nt - 1) & 1;
    LDA(bsel, 0);
    LDB(bsel, 0, b0);
    BARRIER;
    QMFMA(0, 0, b0);
    VMCNT(2);
    BARRIER;
    LDB(bsel, 1, b1);
    BARRIER;
    QMFMA(0, 1, b1);
    VMCNT(0);
    BARRIER;
    LDA(bsel, 1);
    BARRIER;
    QMFMA(1, 0, b0);
    BARRIER;
    QMFMA(1, 1, b1);
  }

  // ---- epilogue ----
  if (EPI == 0) {
    const int which = bcol >> 11;
#pragma unroll
    for (int mf = 0; mf < 8; ++mf) {
      int rbase = brow + wr * 128 + mf * 16 + g * 4;
      int b = rbase >> 11, s = rbase & 2047;
#pragma unroll
      for (int nf = 0; nf < 4; ++nf) {
        int cglob = bcol + wc * 64 + nf * 16 + ln15;
        float bv = bias[cglob];
        int head = (cglob >> 7) & 15;
        int d = cglob & 127;
        if (which == 2) {
          ushort4 pk;
          pk.x = f2bf(acc[mf][nf][0] + bv);
          pk.y = f2bf(acc[mf][nf][1] + bv);
          pk.z = f2bf(acc[mf][nf][2] + bv);
          pk.w = f2bf(acc[mf][nf][3] + bv);
          *(ushort4*)&Ovt[((size_t)(b * NHEADS + head) * HN + d) * SS + s] = pk;
        } else {
          unsigned short* dst = which ? Ok : Oq;
#pragma unroll
          for (int j = 0; j < 4; ++j)
            dst[((size_t)(b * NHEADS + head) * SS + (s + j)) * HN + d] =
                f2bf(acc[mf][nf][j] + bv);
        }
      }
    }
  } else {
#pragma unroll
    for (int mf = 0; mf < 8; ++mf) {
      int rbase = brow + wr * 128 + mf * 16 + g * 4;
#pragma unroll
      for (int nf = 0; nf < 4; ++nf) {
        int cglob = bcol + wc * 64 + nf * 16 + ln15;
        float bv = bias[cglob];
#pragma unroll
        for (int j = 0; j < 4; ++j)
          Of[(size_t)(rbase + j) * N + cglob] = acc[mf][nf][j] + bv;
      }
    }
  }
}

// ---------------- causal flash attention (R3, proven) ----------------
__global__ __launch_bounds__(256, 2) void attn_kernel(
    const unsigned short* __restrict__ Q, const unsigned short* __restrict__ Kb,
    const unsigned short* __restrict__ Vt, unsigned short* __restrict__ ctx) {
  __shared__ __align__(16) unsigned short Klds[64 * 128];    // [key][d] swz
  __shared__ __align__(16) unsigned short Vlds[128 * 64];    // [d][key] swz
  __shared__ __align__(16) unsigned short Plds[4][32 * 72];  // [wave][q][key]
  int t = threadIdx.x, lane = t & 63, wid = t >> 6;
  int g = lane >> 4, ln15 = lane & 15;
  int qi = (int)(gridDim.x - 1) - (int)blockIdx.x;
  int bh = blockIdx.y;
  int q0 = qi * 128;
  int qbase = q0 + wid * 32;
  const unsigned short* Qb = Q + (size_t)bh * SS * HN;
  const unsigned short* Kbh = Kb + (size_t)bh * SS * HN;
  const unsigned short* Vtb = Vt + (size_t)bh * HN * SS;

  bf16x8 qf[2][4];
#pragma unroll
  for (int mr = 0; mr < 2; ++mr) {
    int qrow = qbase + mr * 16 + ln15;
#pragma unroll
    for (int dsi = 0; dsi < 4; ++dsi)
      qf[mr][dsi] = ld8(Qb + (size_t)qrow * HN + dsi * 32 + g * 8);
  }
  f32x4 o[2][8];
#pragma unroll
  for (int mr = 0; mr < 2; ++mr)
#pragma unroll
    for (int n = 0; n < 8; ++n) o[mr][n] = (f32x4){0.f, 0.f, 0.f, 0.f};
  float m_run[2][4], l_run[2][4];
#pragma unroll
  for (int mr = 0; mr < 2; ++mr)
#pragma unroll
    for (int j = 0; j < 4; ++j) { m_run[mr][j] = -1e30f; l_run[mr][j] = 0.f; }
  const float scale = 0.08838834764831845f;
  unsigned short* Pw = Plds[wid];

  int nkt = 2 * qi + 2;
  for (int kt = 0; kt < nkt; ++kt) {
    int k0 = kt * 64;
    __syncthreads();
    {
      const char* Ks = (const char*)(Kbh + (size_t)k0 * HN);
#pragma unroll
      for (int i = 0; i < 4; ++i) {
        int c = t + i * 256;
        int sb = (c * 16) ^ (((c >> 4) & 7) << 4);
        gld_lds16(Ks + sb, (char*)Klds + c * 16);
      }
    }
    {
#pragma unroll
      for (int i = 0; i < 4; ++i) {
        int c = t + i * 256;
        int row = c >> 3;
        int colsw = ((c & 7) * 16) ^ ((row & 7) << 4);
        gld_lds16((const char*)(Vtb + (size_t)row * SS + k0) + colsw,
                  (char*)Vlds + c * 16);
      }
    }
    __syncthreads();
    bool active = (k0 <= qbase + 31);
    if (active) {
      f32x4 sacc[2][4];
#pragma unroll
      for (int mr = 0; mr < 2; ++mr)
#pragma unroll
        for (int f = 0; f < 4; ++f) sacc[mr][f] = (f32x4){0.f, 0.f, 0.f, 0.f};
      __builtin_amdgcn_s_setprio(1);
#pragma unroll
      for (int f = 0; f < 4; ++f) {
        int keyl = f * 16 + ln15;
        int swzk = (keyl & 7) << 4;
#pragma unroll
        for (int dsi = 0; dsi < 4; ++dsi) {
          int off = (keyl * 256 + (dsi * 32 + g * 8) * 2) ^ swzk;
          bf16x8 kf = ld8((const char*)Klds + off);
          sacc[0][f] = __builtin_amdgcn_mfma_f32_16x16x32_bf16(qf[0][dsi], kf, sacc[0][f], 0, 0, 0);
          sacc[1][f] = __builtin_amdgcn_mfma_f32_16x16x32_bf16(qf[1][dsi], kf, sacc[1][f], 0, 0, 0);
        }
      }
      __builtin_amdgcn_s_setprio(0);
      float resc[2][4], rs[2][4];
#pragma unroll
      for (int mr = 0; mr < 2; ++mr) {
        bool needmask = (k0 + 63) > (qbase + mr * 16);
        float pm[4];
#pragma unroll
        for (int j = 0; j < 4; ++j) pm[j] = -1e30f;
#pragma unroll
        for (int f = 0; f < 4; ++f) {
          int key_g = k0 + f * 16 + ln15;
#pragma unroll
          for (int j = 0; j < 4; ++j) {
            float s = sacc[mr][f][j] * scale;
            if (needmask) {
              int q_g = qbase + mr * 16 + g * 4 + j;
              if (key_g > q_g) s = -1e30f;
            }
            sacc[mr][f][j] = s;
            pm[j] = fmaxf(pm[j], s);
          }
        }
#pragma unroll
        for (int j = 0; j < 4; ++j) {
          float v = pm[j];
          v = fmaxf(v, __shfl_xor(v, 1, 16));
          v = fmaxf(v, __shfl_xor(v, 2, 16));
          v = fmaxf(v, __shfl_xor(v, 4, 16));
          v = fmaxf(v, __shfl_xor(v, 8, 16));
          float mn = fmaxf(m_run[mr][j], v);
          resc[mr][j] = __expf(m_run[mr][j] - mn);
          m_run[mr][j] = mn;
          rs[mr][j] = 0.f;
        }
#pragma unroll
        for (int f = 0; f < 4; ++f) {
#pragma unroll
          for (int j = 0; j < 4; ++j) {
            float p = __expf(sacc[mr][f][j] - m_run[mr][j]);
            rs[mr][j] += p;
            Pw[(mr * 16 + g * 4 + j) * 72 + f * 16 + ln15] = f2bf(p);
          }
        }
#pragma unroll
        for (int j = 0; j < 4; ++j) {
          float v = rs[mr][j];
          v += __shfl_xor(v, 1, 16);
          v += __shfl_xor(v, 2, 16);
          v += __shfl_xor(v, 4, 16);
          v += __shfl_xor(v, 8, 16);
          l_run[mr][j] = l_run[mr][j] * resc[mr][j] + v;
        }
#pragma unroll
        for (int n = 0; n < 8; ++n)
#pragma unroll
          for (int j = 0; j < 4; ++j) o[mr][n][j] *= resc[mr][j];
      }
#pragma unroll
      for (int ks = 0; ks < 2; ++ks) {
        bf16x8 pa0 = ld8(&Pw[(size_t)(ln15)*72 + ks * 32 + g * 8]);
        bf16x8 pa1 = ld8(&Pw[(size_t)(16 + ln15) * 72 + ks * 32 + g * 8]);
        __builtin_amdgcn_s_setprio(1);
#pragma unroll
        for (int n = 0; n < 8; ++n) {
          int d = n * 16 + ln15;
          int off = (d * 128 + ks * 64 + g * 16) ^ ((d & 7) << 4);
          bf16x8 vf = ld8((const char*)Vlds + off);
          o[0][n] = __builtin_amdgcn_mfma_f32_16x16x32_bf16(pa0, vf, o[0][n], 0, 0, 0);
          o[1][n] = __builtin_amdgcn_mfma_f32_16x16x32_bf16(pa1, vf, o[1][n], 0, 0, 0);
        }
        __builtin_amdgcn_s_setprio(0);
      }
    }
  }
  int b = bh >> 4, head = bh & 15;
#pragma unroll
  for (int mr = 0; mr < 2; ++mr)
#pragma unroll
    for (int j = 0; j < 4; ++j) {
      int qg = qbase + mr * 16 + g * 4 + j;
      float inv = 1.0f / l_run[mr][j];
      size_t base = ((size_t)(b * SS + qg)) * HDIM + head * HN + ln15;
#pragma unroll
      for (int n = 0; n < 8; ++n)
        ctx[base + n * 16] = f2bf(o[mr][n][j] * inv);
    }
}

extern "C" void kernel_launch(void* const* d_in, const int* in_sizes, int n_in,
                              void* d_out, int out_size, void* d_ws, size_t ws_size,
                              hipStream_t stream) {
  const float* hs = (const float*)d_in[0];
  // d_in[1] = ltor_mask: causal, handled analytically
  const float* w_qkv = (const float*)d_in[2];
  const float* b_qkv = (const float*)d_in[3];
  const float* w_dense = (const float*)d_in[4];
  const float* b_dense = (const float*)d_in[5];
  float* out = (float*)d_out;

  char* ws = (char*)d_ws;
  unsigned short* hsb   = (unsigned short*)(ws);              // reused as ctx
  unsigned short* wqkvT = (unsigned short*)(ws + 33554432);   // reused as wdT
  unsigned short* qb    = (unsigned short*)(ws + 58720256);
  unsigned short* kb    = (unsigned short*)(ws + 92274688);
  unsigned short* vtb   = (unsigned short*)(ws + 125829120);  // V transposed
  unsigned short* ctxb  = hsb;
  unsigned short* wdT   = wqkvT;

  cast_bf16_kernel<<<16384, 256, 0, stream>>>(hs, hsb, 4194304);
  transpose_cast_kernel<<<dim3(96, 32), 256, 0, stream>>>(w_qkv, wqkvT, 2048, 6144);
  gemm256_kernel<0><<<dim3(24, 32), 512, 0, stream>>>(
      hsb, wqkvT, b_qkv, nullptr, qb, kb, vtb, 8192, 6144, 2048);
  transpose_cast_kernel<<<dim3(32, 32), 256, 0, stream>>>(w_dense, wdT, 2048, 2048);
  attn_kernel<<<dim3(16, 64), 256, 0, stream>>>(qb, kb, vtb, ctxb);
  gemm256_kernel<1><<<dim3(8, 32), 512, 0, stream>>>(
      ctxb, wdT, b_dense, out, nullptr, nullptr, nullptr, 8192, 2048, 2048);
}